// Round 14
// baseline (238.745 us; speedup 1.0000x reference)
//
#include <hip/hip_runtime.h>
#include <hip/hip_bf16.h>

// Problem constants (match reference)
constexpr int Bq  = 4;
constexpr int Nn  = 10000;
constexpr int Eq  = 170000;
constexpr int FIN = 256;
constexpr int Ff  = 128;
constexpr int Hh  = 4;
constexpr int C   = Hh * Ff;    // 512 output cols
constexpr float LEAKY = 0.2f;

typedef short short4v __attribute__((ext_vector_type(4)));
typedef short short8  __attribute__((ext_vector_type(8)));
typedef float f32x4   __attribute__((ext_vector_type(4)));

// float -> bf16 bits, round-to-nearest-even
static __device__ __forceinline__ unsigned short f2bf(float f) {
    unsigned int u = __float_as_uint(f);
    u = u + 0x7fffu + ((u >> 16) & 1u);
    return (unsigned short)(u >> 16);
}
static __device__ __forceinline__ float bf2f(unsigned short b) {
    return __uint_as_float(((unsigned int)b) << 16);
}

// ---------- K1: prep — Wf fragment layout, wa/bsd, row_start (one launch) --
// blocks 0..511: Wf; block 512: wa+bsd; blocks 513..552: row_start.
__global__ __launch_bounds__(256) void prep_kernel(
    const float* __restrict__ W, const float* __restrict__ Wattn,
    const float* __restrict__ bmlp, const int* __restrict__ src,
    unsigned short* __restrict__ Wf, float* __restrict__ wa,
    float* __restrict__ bsd, int* __restrict__ row_start)
{
    int bid = blockIdx.x, t = threadIdx.x;
    if (bid < 512) {
        // Wf unit u = ((hi*8 + j)*8 + ks)*64 + quad*16 + ln holds
        // B[k = ks*32 + quad*8 + el][col = hi*128 + j*16 + ln], el = 0..7.
        int cc = bid;  // col = hi*128 + f
        int k = t;
        float v = W[(size_t)(cc >> 7) * FIN * Ff + (size_t)k * Ff + (cc & 127)];
        int w = cc >> 7, j = (cc >> 4) & 7, ln = cc & 15;
        int ks = k >> 5, quad = (k >> 3) & 3, el = k & 7;
        size_t u = ((size_t)((w * 8 + j) * 8 + ks) * 4 + quad) * 16 + ln;
        Wf[u * 8 + el] = f2bf(v);
    } else if (bid == 512) {
        // wa[v][hi][k] = sum_f W[hi][k][f]*a_v[hi][f]; bsd[v][hi] = b.a_v
        int hi = t >> 6, kb = t & 63;
        #pragma unroll
        for (int i = 0; i < 4; ++i) {
            int k = kb + i * 64;
            float ss = 0.f, sd = 0.f;
            const float* wrow = W + ((size_t)hi * FIN + k) * Ff;
            const float* as = Wattn + hi * 2 * Ff;
            const float* ad = as + Ff;
            for (int f = 0; f < Ff; f += 4) {
                float4 wv = *(const float4*)(wrow + f);
                float4 av = *(const float4*)(as + f);
                float4 dv = *(const float4*)(ad + f);
                ss += wv.x * av.x + wv.y * av.y + wv.z * av.z + wv.w * av.w;
                sd += wv.x * dv.x + wv.y * dv.y + wv.z * dv.z + wv.w * dv.w;
            }
            wa[(0 * 4 + hi) * FIN + k] = ss;
            wa[(1 * 4 + hi) * FIN + k] = sd;
        }
        if (t < 8) {
            int v = t & 1, hh = t >> 1;
            float s = 0.f;
            for (int f = 0; f < Ff; ++f)
                s += bmlp[hh * Ff + f] * Wattn[hh * 2 * Ff + v * Ff + f];
            bsd[v * 4 + hh] = s;
        }
    } else {
        int n = (bid - 513) * 256 + t;
        if (n > Nn) return;
        int lo = 0, hi = Eq;
        while (lo < hi) { int mid = (lo + hi) >> 1; if (src[mid] < n) lo = mid + 1; else hi = mid; }
        row_start[n] = lo;
    }
}

// ---------- K2: Xb[n][b][k] = bf16(x[b][n][k]) + fused projections ---------
__global__ __launch_bounds__(256) void xprep_proj_kernel(
    const float* __restrict__ X, const float* __restrict__ wa,
    const float* __restrict__ bsd, unsigned short* __restrict__ Xb,
    float* __restrict__ psT, float* __restrict__ pdT)
{
    int n0 = blockIdx.x * 8;
    int t  = threadIdx.x;
    int r  = t >> 5;          // 0..7 (node within block; half-wave)
    int c  = t & 31;
    int k8 = c * 8;           // 0..248
    float s[8];
    #pragma unroll
    for (int i = 0; i < 8; ++i) s[i] = 0.f;

    #pragma unroll
    for (int b = 0; b < Bq; ++b) {
        const float* p = X + ((size_t)b * Nn + n0 + r) * FIN + k8;
        float4 v0 = *(const float4*)p, v1 = *(const float4*)(p + 4);
        short8 v;
        v[0] = (short)f2bf(v0.x); v[1] = (short)f2bf(v0.y);
        v[2] = (short)f2bf(v0.z); v[3] = (short)f2bf(v0.w);
        v[4] = (short)f2bf(v1.x); v[5] = (short)f2bf(v1.y);
        v[6] = (short)f2bf(v1.z); v[7] = (short)f2bf(v1.w);
        *(short8*)(Xb + ((size_t)(n0 + r) * Bq + b) * FIN + k8) = v;
        if (b == Bq - 1) {
            #pragma unroll
            for (int i = 0; i < 8; ++i) {
                const float* w = wa + (size_t)i * FIN + k8;
                float4 w0 = *(const float4*)w, w1 = *(const float4*)(w + 4);
                s[i] = v0.x * w0.x + v0.y * w0.y + v0.z * w0.z + v0.w * w0.w
                     + v1.x * w1.x + v1.y * w1.y + v1.z * w1.z + v1.w * w1.w;
            }
        }
    }
    #pragma unroll
    for (int off = 1; off < 32; off <<= 1)
        #pragma unroll
        for (int i = 0; i < 8; ++i) s[i] += __shfl_xor(s[i], off, 64);
    if (c == 0) {
        int n = n0 + r;
        #pragma unroll
        for (int hi = 0; hi < 4; ++hi) {
            psT[n * 4 + hi] = s[hi]     + bsd[hi];
            pdT[n * 4 + hi] = s[4 + hi] + bsd[4 + hi];
        }
    }
}

// ---------- K3: edge scores -> RAW e + denom (single pass, contiguous) -----
// Wave per node (4/block). Normalization folds into the fused gather.
__global__ __launch_bounds__(256) void edge_denom_kernel(
    const int* __restrict__ dst, const int* __restrict__ row_start,
    const float* __restrict__ psT, const float* __restrict__ pdT,
    float* __restrict__ eed, float* __restrict__ denom)
{
    int wv = threadIdx.x >> 6, t = threadIdx.x & 63;
    int n = blockIdx.x * 4 + wv;
    int e0 = row_start[n], e1 = row_start[n + 1];
    float4 ps = *(const float4*)(psT + (size_t)n * 4);
    float4 acc = {0.f, 0.f, 0.f, 0.f};
    for (int e = e0 + t; e < e1; e += 64) {
        int d = dst[e];
        float4 pd = *(const float4*)(pdT + (size_t)d * 4);
        float4 ev;
        { float sc = ps.x + pd.x; float lr = sc > 0.f ? sc : LEAKY * sc;
          ev.x = __expf(fminf(fmaxf(lr, -2.f), 2.f)); }
        { float sc = ps.y + pd.y; float lr = sc > 0.f ? sc : LEAKY * sc;
          ev.y = __expf(fminf(fmaxf(lr, -2.f), 2.f)); }
        { float sc = ps.z + pd.z; float lr = sc > 0.f ? sc : LEAKY * sc;
          ev.z = __expf(fminf(fmaxf(lr, -2.f), 2.f)); }
        { float sc = ps.w + pd.w; float lr = sc > 0.f ? sc : LEAKY * sc;
          ev.w = __expf(fminf(fmaxf(lr, -2.f), 2.f)); }
        *(float4*)(eed + (size_t)e * 4) = ev;
        acc.x += ev.x; acc.y += ev.y; acc.z += ev.z; acc.w += ev.w;
    }
    #pragma unroll
    for (int off = 1; off < 64; off <<= 1) {
        acc.x += __shfl_xor(acc.x, off, 64);
        acc.y += __shfl_xor(acc.y, off, 64);
        acc.z += __shfl_xor(acc.z, off, 64);
        acc.w += __shfl_xor(acc.w, off, 64);
    }
    if (t == 0) *(float4*)(denom + (size_t)n * 4) = acc;
}

// ---------- K4: FUSED gather + GEMM2 — 2 nodes/block for natural 8-block/CU
// 5000 blocks. Half-block h = t>>7 (128 threads) owns node n0+h; thread
// slot s = t&127 owns a 16B slice (b = s>>5, 8-k) of the 2KB node row.
// Same proven 8/4/1 x 16B ladder as the 77.5us round-8 kernel; the ONLY
// structural delta is block granularity 4->2 nodes (split at the existing
// half-block seam). Residency now follows from DEFAULT limits, not an
// aggressive waves/EU attribute (the (256,5) attribute caused replay-
// nondeterministic corruption — never schedule LDS to exactly 160KiB/CU):
//   VGPR ~64 (measured round 8) -> 8 waves/EU; LDS 16KB -> 10 blocks;
//   => 8 blocks/CU resident (32 waves, 2x the 4-node version).
// MFMA: 16x16 tile, 8 valid rows (A-row wraps ln&7), quad<2 epilogue —
// hardware-verified correct in round 6. Dead MFMA rows cost ~0 (MfmaUtil 5%).
__global__ __launch_bounds__(256, 4) void gather_gemm_kernel(
    const unsigned short* __restrict__ Xb, const float* __restrict__ eed,
    const int* __restrict__ row_start, const int* __restrict__ dst,
    const unsigned short* __restrict__ Wf, const float* __restrict__ bias,
    const float* __restrict__ denom, float* __restrict__ out)
{
    __shared__ unsigned short As[Hh * 8 * 256];   // 16 KB

    const int n0  = blockIdx.x * 2;
    const int t   = threadIdx.x;
    const int h   = t >> 7;           // half-block -> node
    const int s   = t & 127;
    const int b   = s >> 5;           // batch
    const int k0  = (s & 31) * 8;     // short offset within 256-short row
    const int off = s * 8;            // = b*256 + k0 shorts into node row

    const int n  = n0 + h;
    const int e0 = row_start[n], e1 = row_start[n + 1];

    const float4* eed4 = (const float4*)eed;

    float acc[4][8];                  // [hi][j]
    #pragma unroll
    for (int hi = 0; hi < 4; ++hi)
        #pragma unroll
        for (int j = 0; j < 8; ++j) acc[hi][j] = 0.f;

    int e = e0;
    // ---- 8-edge tier: 8 x 16B gathered loads in flight ----
    for (; e + 8 <= e1; e += 8) {
        int d[8];
        #pragma unroll
        for (int i = 0; i < 8; ++i) d[i] = dst[e + i];
        short8 v[8];
        #pragma unroll
        for (int i = 0; i < 8; ++i)
            v[i] = *(const short8*)(Xb + (size_t)d[i] * 1024 + off);
        float4 ev[8];
        #pragma unroll
        for (int i = 0; i < 8; ++i) ev[i] = eed4[e + i];
        #pragma unroll
        for (int j = 0; j < 8; ++j) {
            float s0 = 0.f, s1 = 0.f, s2 = 0.f, s3 = 0.f;
            #pragma unroll
            for (int i = 0; i < 8; ++i) {
                float f = bf2f((unsigned short)v[i][j]);
                s0 += f * ev[i].x; s1 += f * ev[i].y;
                s2 += f * ev[i].z; s3 += f * ev[i].w;
            }
            acc[0][j] += s0; acc[1][j] += s1;
            acc[2][j] += s2; acc[3][j] += s3;
        }
    }
    // ---- 4-edge tier ----
    for (; e + 4 <= e1; e += 4) {
        int d[4];
        #pragma unroll
        for (int i = 0; i < 4; ++i) d[i] = dst[e + i];
        short8 v[4];
        #pragma unroll
        for (int i = 0; i < 4; ++i)
            v[i] = *(const short8*)(Xb + (size_t)d[i] * 1024 + off);
        float4 ev[4];
        #pragma unroll
        for (int i = 0; i < 4; ++i) ev[i] = eed4[e + i];
        #pragma unroll
        for (int j = 0; j < 8; ++j) {
            float s0 = 0.f, s1 = 0.f, s2 = 0.f, s3 = 0.f;
            #pragma unroll
            for (int i = 0; i < 4; ++i) {
                float f = bf2f((unsigned short)v[i][j]);
                s0 += f * ev[i].x; s1 += f * ev[i].y;
                s2 += f * ev[i].z; s3 += f * ev[i].w;
            }
            acc[0][j] += s0; acc[1][j] += s1;
            acc[2][j] += s2; acc[3][j] += s3;
        }
    }
    // ---- singles (<=3) ----
    for (; e < e1; ++e) {
        int d0 = dst[e];
        short8 v0 = *(const short8*)(Xb + (size_t)d0 * 1024 + off);
        float4 ev0 = eed4[e];
        #pragma unroll
        for (int j = 0; j < 8; ++j) {
            float f = bf2f((unsigned short)v0[j]);
            acc[0][j] += f * ev0.x; acc[1][j] += f * ev0.y;
            acc[2][j] += f * ev0.z; acc[3][j] += f * ev0.w;
        }
    }

    // fold normalization: acc * (denom != 0 ? 1/denom : 0); deposit bf16
    {
        float4 dn = *(const float4*)(denom + (size_t)n * 4);
        float inv[4];
        inv[0] = dn.x != 0.f ? 1.f / dn.x : 0.f;
        inv[1] = dn.y != 0.f ? 1.f / dn.y : 0.f;
        inv[2] = dn.z != 0.f ? 1.f / dn.z : 0.f;
        inv[3] = dn.w != 0.f ? 1.f / dn.w : 0.f;
        const int row = h * 4 + b;        // 0..7
        const int swz = row << 3;         // 16B-granular XOR swizzle (bits 3-5)
        #pragma unroll
        for (int hi = 0; hi < 4; ++hi) {
            short8 o;
            #pragma unroll
            for (int j = 0; j < 8; ++j) o[j] = (short)f2bf(acc[hi][j] * inv[hi]);
            *(short8*)&As[(hi * 2048 + row * 256 + k0) ^ swz] = o;
        }
    }
    __syncthreads();

    // ---- MFMA phase: wave = head; A rows wrap ln&7 (8 valid rows) ----
    const int lane = t & 63;
    const int hi   = t >> 6;
    const int quad = lane >> 4, ln = lane & 15;
    const int lnr  = ln & 7;

    f32x4 macc[8];
    #pragma unroll
    for (int j = 0; j < 8; ++j) macc[j] = (f32x4){0.f, 0.f, 0.f, 0.f};

    const short8* Wf8 = (const short8*)Wf;
    #pragma unroll
    for (int ks = 0; ks < 8; ++ks) {
        short8 a = *(const short8*)&As[(hi * 2048 + lnr * 256 + ks * 32 + quad * 8) ^ (lnr << 3)];
        #pragma unroll
        for (int j = 0; j < 8; ++j) {
            short8 bf = Wf8[(size_t)((hi * 8 + j) * 8 + ks) * 64 + lane];
            macc[j] = __builtin_amdgcn_mfma_f32_16x16x32_bf16(a, bf, macc[j], 0, 0, 0);
        }
    }

    // epilogue: D row m = quad*4 + r; valid m<8 -> quad<2; node n0+quad,
    // batch r. Rows 8-15 are duplicates - skip.
    if (quad < 2) {
        const int nn = n0 + quad;
        const float flag = denom[(size_t)nn * 4 + hi] != 0.f ? 1.f : 0.f;
        #pragma unroll
        for (int j = 0; j < 8; ++j) {
            int colf = j * 16 + ln;     // col within head, 0..127
            float bv = bias[hi * Ff + colf] * flag;
            #pragma unroll
            for (int r = 0; r < 4; ++r) {
                out[((size_t)r * Nn + nn) * C + hi * Ff + colf] = macc[j][r] + bv;
            }
        }
    }
}

// -------------------- launch --------------------
extern "C" void kernel_launch(void* const* d_in, const int* in_sizes, int n_in,
                              void* d_out, int out_size, void* d_ws, size_t ws_size,
                              hipStream_t stream)
{
    const float* x      = (const float*)d_in[0]; // (B,N,256)
    const float* W_mlp  = (const float*)d_in[1]; // (H,256,128)
    const float* b_mlp  = (const float*)d_in[2]; // (H,128)
    const float* W_attn = (const float*)d_in[3]; // (H,256,1)
    const int*   src    = (const int*)d_in[4];   // (E,)
    const int*   dst    = (const int*)d_in[5];   // (E,)
    float* out = (float*)d_out;                  // (B,N,512)

    // workspace layout
    unsigned short* Xb  = (unsigned short*)d_ws;          // 10000*4*256 bf16 = 20.48 MB
    unsigned short* Wf  = Xb + (size_t)Nn * Bq * FIN;     // 512*256 bf16
    float* eed   = (float*)(Wf + (size_t)C * FIN);        // E*4 floats (raw e)
    float* psT   = eed + (size_t)Eq * 4;                  // N*4
    float* pdT   = psT + (size_t)Nn * 4;                  // N*4
    float* denom = pdT + (size_t)Nn * 4;                  // N*4
    float* wa    = denom + (size_t)Nn * 4;                // 2*4*256
    float* bsd   = wa + 2 * 4 * FIN;                      // 8 (pad 16)
    int*   row_st = (int*)(bsd + 16);                     // N+1

    hipLaunchKernelGGL(prep_kernel, dim3(553), dim3(256), 0, stream,
                       W_mlp, W_attn, b_mlp, src, Wf, wa, bsd, row_st);
    hipLaunchKernelGGL(xprep_proj_kernel, dim3(Nn / 8), dim3(256), 0, stream,
                       x, wa, bsd, Xb, psT, pdT);
    hipLaunchKernelGGL(edge_denom_kernel, dim3(Nn / 4), dim3(256), 0, stream,
                       dst, row_st, psT, pdT, eed, denom);
    hipLaunchKernelGGL(gather_gemm_kernel, dim3(Nn / 2), dim3(256), 0, stream,
                       Xb, eed, row_st, dst, Wf, b_mlp, denom, out);
}

// Round 15
// 212.559 us; speedup vs baseline: 1.1232x; 1.1232x over previous
//
#include <hip/hip_runtime.h>
#include <hip/hip_bf16.h>

// Problem constants (match reference)
constexpr int Bq  = 4;
constexpr int Nn  = 10000;
constexpr int Eq  = 170000;
constexpr int FIN = 256;
constexpr int Ff  = 128;
constexpr int Hh  = 4;
constexpr int C   = Hh * Ff;    // 512 output cols
constexpr float LEAKY = 0.2f;

typedef short short4v __attribute__((ext_vector_type(4)));
typedef short short8  __attribute__((ext_vector_type(8)));
typedef float f32x4   __attribute__((ext_vector_type(4)));

// float -> bf16 bits, round-to-nearest-even
static __device__ __forceinline__ unsigned short f2bf(float f) {
    unsigned int u = __float_as_uint(f);
    u = u + 0x7fffu + ((u >> 16) & 1u);
    return (unsigned short)(u >> 16);
}
static __device__ __forceinline__ float bf2f(unsigned short b) {
    return __uint_as_float(((unsigned int)b) << 16);
}

// ---------- K1: prep — Wf fragment layout, wa/bsd, row_start (one launch) --
// blocks 0..511: Wf; block 512: wa+bsd; blocks 513..552: row_start.
__global__ __launch_bounds__(256) void prep_kernel(
    const float* __restrict__ W, const float* __restrict__ Wattn,
    const float* __restrict__ bmlp, const int* __restrict__ src,
    unsigned short* __restrict__ Wf, float* __restrict__ wa,
    float* __restrict__ bsd, int* __restrict__ row_start)
{
    int bid = blockIdx.x, t = threadIdx.x;
    if (bid < 512) {
        // Wf unit u = ((hi*8 + j)*8 + ks)*64 + quad*16 + ln holds
        // B[k = ks*32 + quad*8 + el][col = hi*128 + j*16 + ln], el = 0..7.
        int cc = bid;  // col = hi*128 + f
        int k = t;
        float v = W[(size_t)(cc >> 7) * FIN * Ff + (size_t)k * Ff + (cc & 127)];
        int w = cc >> 7, j = (cc >> 4) & 7, ln = cc & 15;
        int ks = k >> 5, quad = (k >> 3) & 3, el = k & 7;
        size_t u = ((size_t)((w * 8 + j) * 8 + ks) * 4 + quad) * 16 + ln;
        Wf[u * 8 + el] = f2bf(v);
    } else if (bid == 512) {
        // wa[v][hi][k] = sum_f W[hi][k][f]*a_v[hi][f]; bsd[v][hi] = b.a_v
        int hi = t >> 6, kb = t & 63;
        #pragma unroll
        for (int i = 0; i < 4; ++i) {
            int k = kb + i * 64;
            float ss = 0.f, sd = 0.f;
            const float* wrow = W + ((size_t)hi * FIN + k) * Ff;
            const float* as = Wattn + hi * 2 * Ff;
            const float* ad = as + Ff;
            for (int f = 0; f < Ff; f += 4) {
                float4 wv = *(const float4*)(wrow + f);
                float4 av = *(const float4*)(as + f);
                float4 dv = *(const float4*)(ad + f);
                ss += wv.x * av.x + wv.y * av.y + wv.z * av.z + wv.w * av.w;
                sd += wv.x * dv.x + wv.y * dv.y + wv.z * dv.z + wv.w * dv.w;
            }
            wa[(0 * 4 + hi) * FIN + k] = ss;
            wa[(1 * 4 + hi) * FIN + k] = sd;
        }
        if (t < 8) {
            int v = t & 1, hh = t >> 1;
            float s = 0.f;
            for (int f = 0; f < Ff; ++f)
                s += bmlp[hh * Ff + f] * Wattn[hh * 2 * Ff + v * Ff + f];
            bsd[v * 4 + hh] = s;
        }
    } else {
        int n = (bid - 513) * 256 + t;
        if (n > Nn) return;
        int lo = 0, hi = Eq;
        while (lo < hi) { int mid = (lo + hi) >> 1; if (src[mid] < n) lo = mid + 1; else hi = mid; }
        row_start[n] = lo;
    }
}

// ---------- K2: Xb[n][b][k] = bf16(x[b][n][k]) + fused projections ---------
__global__ __launch_bounds__(256) void xprep_proj_kernel(
    const float* __restrict__ X, const float* __restrict__ wa,
    const float* __restrict__ bsd, unsigned short* __restrict__ Xb,
    float* __restrict__ psT, float* __restrict__ pdT)
{
    int n0 = blockIdx.x * 8;
    int t  = threadIdx.x;
    int r  = t >> 5;          // 0..7 (node within block; half-wave)
    int c  = t & 31;
    int k8 = c * 8;           // 0..248
    float s[8];
    #pragma unroll
    for (int i = 0; i < 8; ++i) s[i] = 0.f;

    #pragma unroll
    for (int b = 0; b < Bq; ++b) {
        const float* p = X + ((size_t)b * Nn + n0 + r) * FIN + k8;
        float4 v0 = *(const float4*)p, v1 = *(const float4*)(p + 4);
        short8 v;
        v[0] = (short)f2bf(v0.x); v[1] = (short)f2bf(v0.y);
        v[2] = (short)f2bf(v0.z); v[3] = (short)f2bf(v0.w);
        v[4] = (short)f2bf(v1.x); v[5] = (short)f2bf(v1.y);
        v[6] = (short)f2bf(v1.z); v[7] = (short)f2bf(v1.w);
        *(short8*)(Xb + ((size_t)(n0 + r) * Bq + b) * FIN + k8) = v;
        if (b == Bq - 1) {
            #pragma unroll
            for (int i = 0; i < 8; ++i) {
                const float* w = wa + (size_t)i * FIN + k8;
                float4 w0 = *(const float4*)w, w1 = *(const float4*)(w + 4);
                s[i] = v0.x * w0.x + v0.y * w0.y + v0.z * w0.z + v0.w * w0.w
                     + v1.x * w1.x + v1.y * w1.y + v1.z * w1.z + v1.w * w1.w;
            }
        }
    }
    #pragma unroll
    for (int off = 1; off < 32; off <<= 1)
        #pragma unroll
        for (int i = 0; i < 8; ++i) s[i] += __shfl_xor(s[i], off, 64);
    if (c == 0) {
        int n = n0 + r;
        #pragma unroll
        for (int hi = 0; hi < 4; ++hi) {
            psT[n * 4 + hi] = s[hi]     + bsd[hi];
            pdT[n * 4 + hi] = s[4 + hi] + bsd[4 + hi];
        }
    }
}

// ---------- K3: edge scores -> RAW e + denom (single pass, contiguous) -----
// Wave per node (4/block). Normalization folds into the fused gather.
__global__ __launch_bounds__(256) void edge_denom_kernel(
    const int* __restrict__ dst, const int* __restrict__ row_start,
    const float* __restrict__ psT, const float* __restrict__ pdT,
    float* __restrict__ eed, float* __restrict__ denom)
{
    int wv = threadIdx.x >> 6, t = threadIdx.x & 63;
    int n = blockIdx.x * 4 + wv;
    int e0 = row_start[n], e1 = row_start[n + 1];
    float4 ps = *(const float4*)(psT + (size_t)n * 4);
    float4 acc = {0.f, 0.f, 0.f, 0.f};
    for (int e = e0 + t; e < e1; e += 64) {
        int d = dst[e];
        float4 pd = *(const float4*)(pdT + (size_t)d * 4);
        float4 ev;
        { float sc = ps.x + pd.x; float lr = sc > 0.f ? sc : LEAKY * sc;
          ev.x = __expf(fminf(fmaxf(lr, -2.f), 2.f)); }
        { float sc = ps.y + pd.y; float lr = sc > 0.f ? sc : LEAKY * sc;
          ev.y = __expf(fminf(fmaxf(lr, -2.f), 2.f)); }
        { float sc = ps.z + pd.z; float lr = sc > 0.f ? sc : LEAKY * sc;
          ev.z = __expf(fminf(fmaxf(lr, -2.f), 2.f)); }
        { float sc = ps.w + pd.w; float lr = sc > 0.f ? sc : LEAKY * sc;
          ev.w = __expf(fminf(fmaxf(lr, -2.f), 2.f)); }
        *(float4*)(eed + (size_t)e * 4) = ev;
        acc.x += ev.x; acc.y += ev.y; acc.z += ev.z; acc.w += ev.w;
    }
    #pragma unroll
    for (int off = 1; off < 64; off <<= 1) {
        acc.x += __shfl_xor(acc.x, off, 64);
        acc.y += __shfl_xor(acc.y, off, 64);
        acc.z += __shfl_xor(acc.z, off, 64);
        acc.w += __shfl_xor(acc.w, off, 64);
    }
    if (t == 0) *(float4*)(denom + (size_t)n * 4) = acc;
}

// ---------- K4: FUSED gather + GEMM2 (session-best round-7 structure) ------
// Block = 4 nodes (16 GEMM rows). Per node, all 256 threads gather with an
// 8/4/1 unroll ladder: 8 gathered short4 (8B) loads issued back-to-back per
// thread. __launch_bounds__(256,4): VGPR cap 128, no spill (measured VGPR=60,
// WRITE exactly 80MB). LDS 32 KB swizzled, 4 blocks/CU.
// MEASURED 76.5us K4 / 212.6us total (round 7) — best of 14 rounds.
// Findings locked in: deeper(>8)/wider(16B) per-wave MLP neutral (R8);
// more blocks/CU regresses (R14: halves edge streams, doubles MFMA+barrier
// overhead); (256,5)+160KiB-LDS corrupts (R11); (256,6) cap-85 spills (R6).
// K4 sits at the L3 random-service ceiling: 150MB L2-miss traffic
// (Xb 20.5MB sampled ~17x, >> 4MB/XCD L2) at ~2-3 TB/s effective.
__global__ __launch_bounds__(256, 4) void gather_gemm_kernel(
    const unsigned short* __restrict__ Xb, const float* __restrict__ eed,
    const int* __restrict__ row_start, const int* __restrict__ dst,
    const unsigned short* __restrict__ Wf, const float* __restrict__ bias,
    const float* __restrict__ denom, float* __restrict__ out)
{
    __shared__ unsigned short As[Hh * 16 * 256];   // 32 KB

    const int n0  = blockIdx.x * 4;
    const int t   = threadIdx.x;
    const int b   = t >> 6;         // batch (wave index in gather phase)
    const int off = t * 4;          // = b*256 + k0, shorts into node row
    const int k0  = (t & 63) * 4;

    const float4* eed4 = (const float4*)eed;

    for (int nl = 0; nl < 4; ++nl) {
        const int n  = n0 + nl;
        const int e0 = row_start[n], e1 = row_start[n + 1];

        float acc[4][4];
        #pragma unroll
        for (int hi = 0; hi < 4; ++hi)
            #pragma unroll
            for (int j = 0; j < 4; ++j) acc[hi][j] = 0.f;

        int e = e0;
        // ---- 8-edge unroll: 8 loads in flight ----
        for (; e + 8 <= e1; e += 8) {
            int d[8];
            #pragma unroll
            for (int i = 0; i < 8; ++i) d[i] = dst[e + i];
            short4v v[8];
            #pragma unroll
            for (int i = 0; i < 8; ++i)
                v[i] = *(const short4v*)(Xb + (size_t)d[i] * 1024 + off);
            float4 ev[8];
            #pragma unroll
            for (int i = 0; i < 8; ++i) ev[i] = eed4[e + i];
            #pragma unroll
            for (int j = 0; j < 4; ++j) {
                float s0 = 0.f, s1 = 0.f, s2 = 0.f, s3 = 0.f;
                #pragma unroll
                for (int i = 0; i < 8; ++i) {
                    float f = bf2f((unsigned short)v[i][j]);
                    s0 += f * ev[i].x; s1 += f * ev[i].y;
                    s2 += f * ev[i].z; s3 += f * ev[i].w;
                }
                acc[0][j] += s0; acc[1][j] += s1;
                acc[2][j] += s2; acc[3][j] += s3;
            }
        }
        // ---- 4-edge tier ----
        for (; e + 4 <= e1; e += 4) {
            int d[4];
            #pragma unroll
            for (int i = 0; i < 4; ++i) d[i] = dst[e + i];
            short4v v[4];
            #pragma unroll
            for (int i = 0; i < 4; ++i)
                v[i] = *(const short4v*)(Xb + (size_t)d[i] * 1024 + off);
            float4 ev[4];
            #pragma unroll
            for (int i = 0; i < 4; ++i) ev[i] = eed4[e + i];
            #pragma unroll
            for (int j = 0; j < 4; ++j) {
                float s0 = 0.f, s1 = 0.f, s2 = 0.f, s3 = 0.f;
                #pragma unroll
                for (int i = 0; i < 4; ++i) {
                    float f = bf2f((unsigned short)v[i][j]);
                    s0 += f * ev[i].x; s1 += f * ev[i].y;
                    s2 += f * ev[i].z; s3 += f * ev[i].w;
                }
                acc[0][j] += s0; acc[1][j] += s1;
                acc[2][j] += s2; acc[3][j] += s3;
            }
        }
        // ---- singles (<=3) ----
        for (; e < e1; ++e) {
            int d0 = dst[e];
            short4v v0 = *(const short4v*)(Xb + (size_t)d0 * 1024 + off);
            float4 ev0 = eed4[e];
            #pragma unroll
            for (int j = 0; j < 4; ++j) {
                float f = bf2f((unsigned short)v0[j]);
                acc[0][j] += f * ev0.x; acc[1][j] += f * ev0.y;
                acc[2][j] += f * ev0.z; acc[3][j] += f * ev0.w;
            }
        }

        // fold normalization: acc * (denom != 0 ? 1/denom : 0)
        float4 dn = *(const float4*)(denom + (size_t)n * 4);
        float inv[4];
        inv[0] = dn.x != 0.f ? 1.f / dn.x : 0.f;
        inv[1] = dn.y != 0.f ? 1.f / dn.y : 0.f;
        inv[2] = dn.z != 0.f ? 1.f / dn.z : 0.f;
        inv[3] = dn.w != 0.f ? 1.f / dn.w : 0.f;

        const int row = nl * 4 + b;   // GEMM row m within tile: node nl, batch b
        const int swz = (row & 7) << 3;
        #pragma unroll
        for (int hi = 0; hi < 4; ++hi) {
            short4v o;
            #pragma unroll
            for (int j = 0; j < 4; ++j) o[j] = (short)f2bf(acc[hi][j] * inv[hi]);
            *(short4v*)&As[(hi * 4096 + row * 256 + k0) ^ swz] = o;
        }
    }
    __syncthreads();

    // ---- MFMA phase: wave = head ----
    const int lane = t & 63;
    const int hi   = t >> 6;
    const int quad = lane >> 4, ln = lane & 15;
    const int rswz = (ln & 7) << 3;

    f32x4 macc[8];
    #pragma unroll
    for (int j = 0; j < 8; ++j) macc[j] = (f32x4){0.f, 0.f, 0.f, 0.f};

    const short8* Wf8 = (const short8*)Wf;
    #pragma unroll
    for (int ks = 0; ks < 8; ++ks) {
        short8 a = *(const short8*)&As[(hi * 4096 + ln * 256 + ks * 32 + quad * 8) ^ rswz];
        #pragma unroll
        for (int j = 0; j < 8; ++j) {
            short8 bf = Wf8[(size_t)((hi * 8 + j) * 8 + ks) * 64 + lane];
            macc[j] = __builtin_amdgcn_mfma_f32_16x16x32_bf16(a, bf, macc[j], 0, 0, 0);
        }
    }

    // epilogue: row m = quad*4 + r -> node n0+quad, batch r
    const int nn = n0 + quad;
    const float flag = denom[(size_t)nn * 4 + hi] != 0.f ? 1.f : 0.f;
    #pragma unroll
    for (int j = 0; j < 8; ++j) {
        int colf = j * 16 + ln;     // col within head, 0..127
        float bv = bias[hi * Ff + colf] * flag;
        #pragma unroll
        for (int r = 0; r < 4; ++r) {
            out[((size_t)r * Nn + nn) * C + hi * Ff + colf] = macc[j][r] + bv;
        }
    }
}

// -------------------- launch --------------------
extern "C" void kernel_launch(void* const* d_in, const int* in_sizes, int n_in,
                              void* d_out, int out_size, void* d_ws, size_t ws_size,
                              hipStream_t stream)
{
    const float* x      = (const float*)d_in[0]; // (B,N,256)
    const float* W_mlp  = (const float*)d_in[1]; // (H,256,128)
    const float* b_mlp  = (const float*)d_in[2]; // (H,128)
    const float* W_attn = (const float*)d_in[3]; // (H,256,1)
    const int*   src    = (const int*)d_in[4];   // (E,)
    const int*   dst    = (const int*)d_in[5];   // (E,)
    float* out = (float*)d_out;                  // (B,N,512)

    // workspace layout
    unsigned short* Xb  = (unsigned short*)d_ws;          // 10000*4*256 bf16 = 20.48 MB
    unsigned short* Wf  = Xb + (size_t)Nn * Bq * FIN;     // 512*256 bf16
    float* eed   = (float*)(Wf + (size_t)C * FIN);        // E*4 floats (raw e)
    float* psT   = eed + (size_t)Eq * 4;                  // N*4
    float* pdT   = psT + (size_t)Nn * 4;                  // N*4
    float* denom = pdT + (size_t)Nn * 4;                  // N*4
    float* wa    = denom + (size_t)Nn * 4;                // 2*4*256
    float* bsd   = wa + 2 * 4 * FIN;                      // 8 (pad 16)
    int*   row_st = (int*)(bsd + 16);                     // N+1

    hipLaunchKernelGGL(prep_kernel, dim3(553), dim3(256), 0, stream,
                       W_mlp, W_attn, b_mlp, src, Wf, wa, bsd, row_st);
    hipLaunchKernelGGL(xprep_proj_kernel, dim3(Nn / 8), dim3(256), 0, stream,
                       x, wa, bsd, Xb, psT, pdT);
    hipLaunchKernelGGL(edge_denom_kernel, dim3(Nn / 4), dim3(256), 0, stream,
                       dst, row_st, psT, pdT, eed, denom);
    hipLaunchKernelGGL(gather_gemm_kernel, dim3(Nn / 4), dim3(256), 0, stream,
                       Xb, eed, row_st, dst, Wf, b_mlp, denom, out);
}